// Round 1
// baseline (2277.991 us; speedup 1.0000x reference)
//
#include <hip/hip_runtime.h>
#include <hip/hip_bf16.h>

#define HID    256
#define AFD    133
#define KA_PAD 160
#define KB_PAD 32
#define MAXNB  16
#define BN_EPS 1e-5f

typedef __attribute__((ext_vector_type(8))) __bf16 bf16x8;
typedef __attribute__((ext_vector_type(4))) float  f32x4;

__device__ __forceinline__ unsigned short f2bf(float x){
  union { __hip_bfloat16 b; unsigned short u; } cv;
  cv.b = __float2bfloat16(x);
  return cv.u;
}

// XOR swizzle on 16B blocks within a row-stripe: kills ds_read_b128 bank conflicts
__device__ __forceinline__ unsigned swzb(int row, int kbyte, int rowStrideB){
  return (unsigned)(row*rowStrideB + kbyte) ^ (unsigned)((row & 7) << 4);
}

__device__ __forceinline__ f32x4 mfma16(bf16x8 a, bf16x8 b, f32x4 c){
  return __builtin_amdgcn_mfma_f32_16x16x32_bf16(a, b, c, 0, 0, 0);
}

// ---------------- packing kernels ----------------

// W[K][Ncols] f32 -> WT[Ncols][Kpad] bf16 (zero-padded K)
__global__ void pack_wT(const float* __restrict__ W, unsigned short* __restrict__ WT,
                        int K, int Ncols, int Kpad){
  int total = Ncols * Kpad;
  for(int idx = blockIdx.x*blockDim.x + threadIdx.x; idx < total; idx += gridDim.x*blockDim.x){
    int col = idx / Kpad, k = idx - col*Kpad;
    float v = (k < K) ? W[(size_t)k*Ncols + col] : 0.f;
    WT[idx] = f2bf(v);
  }
}

// f_bonds (E,15) f32 -> eb (E,16) bf16 with zero last column
__global__ void pack_eb(const float* __restrict__ fb, unsigned short* __restrict__ eb, int E){
  int total = E*16;
  for(int idx = blockIdx.x*blockDim.x + threadIdx.x; idx < total; idx += gridDim.x*blockDim.x){
    int e = idx >> 4, k = idx & 15;
    float v = (k < 15) ? fb[(size_t)e*15 + k] : 0.f;
    eb[idx] = f2bf(v);
  }
}

// to[a2b[i][j]] = i for a2b>0 (to pre-zeroed)
__global__ void build_to(const int* __restrict__ a2b, int* __restrict__ to, int N){
  int total = N*MAXNB;
  for(int idx = blockIdx.x*blockDim.x + threadIdx.x; idx < total; idx += gridDim.x*blockDim.x){
    int b = a2b[idx];
    if(b > 0) to[b] = idx / MAXNB;
  }
}

// self-loop embedding per layer: sl = relu(w1[l][15]+b1[l]) @ w2[l] + b2[l]
__global__ void sl_emb_kernel(const float* __restrict__ w1, const float* __restrict__ b1,
                              const float* __restrict__ w2, const float* __restrict__ b2,
                              float* __restrict__ sl){
  int l = blockIdx.x, t = threadIdx.x;
  __shared__ float hid[HID];
  float hv = w1[((size_t)l*16 + 15)*HID + t] + b1[(size_t)l*HID + t];
  hid[t] = hv > 0.f ? hv : 0.f;
  __syncthreads();
  const float* W2 = w2 + (size_t)l*HID*HID;
  float acc = b2[(size_t)l*HID + t];
  for(int k=0;k<HID;k++) acc += hid[k] * W2[(size_t)k*HID + t];
  sl[(size_t)l*HID + t] = acc;
}

// ---------------- h0 = f_atoms @ w_atom ----------------

__global__ __launch_bounds__(256,2) void atom_embed(
    const float* __restrict__ fat, const unsigned short* __restrict__ wAT,
    float* __restrict__ h, int N)
{
  __shared__ alignas(16) unsigned short sA[64*KA_PAD];
  const int t = threadIdx.x;
  const int m0 = blockIdx.x*64;
  for(int i=t; i<64*KA_PAD; i+=256){
    int row = i / KA_PAD;
    int k   = i - row*KA_PAD;
    int gr  = m0 + row;
    float v = (gr < N && k < AFD) ? fat[(size_t)gr*AFD + k] : 0.f;
    *(unsigned short*)((char*)sA + swzb(row, k*2, KA_PAD*2)) = f2bf(v);
  }
  __syncthreads();
  const int w = t>>6, l = t&63, lg = l>>4, lc = l&15;
  const f32x4 z4 = {0.f,0.f,0.f,0.f};
  f32x4 acc[4][4];
#pragma unroll
  for(int fi=0;fi<4;fi++)
#pragma unroll
    for(int fj=0;fj<4;fj++) acc[fi][fj] = z4;
  for(int k0=0;k0<KA_PAD;k0+=32){
    bf16x8 a[4], b[4];
#pragma unroll
    for(int fi=0;fi<4;fi++)
      a[fi] = *(const bf16x8*)((const char*)sA + swzb(fi*16+lc, (k0+lg*8)*2, KA_PAD*2));
#pragma unroll
    for(int fj=0;fj<4;fj++){
      int col = w*64 + fj*16 + lc;
      b[fj] = *(const bf16x8*)(wAT + (size_t)col*KA_PAD + k0 + lg*8);
    }
#pragma unroll
    for(int fi=0;fi<4;fi++)
#pragma unroll
      for(int fj=0;fj<4;fj++)
        acc[fi][fj] = mfma16(a[fi], b[fj], acc[fi][fj]);
  }
#pragma unroll
  for(int fj=0;fj<4;fj++){
    int col = w*64 + fj*16 + lc;
#pragma unroll
    for(int fi=0;fi<4;fi++)
#pragma unroll
      for(int r=0;r<4;r++){
        int gr = m0 + fi*16 + lg*4 + r;
        if(gr < N) h[(size_t)gr*HID + col] = acc[fi][fj][r];
      }
  }
}

// ---------------- aggr = BNprev(h) + sl ----------------

__global__ void aggr_init(const float* __restrict__ h, const float* __restrict__ sl,
                          const float* __restrict__ musig, const float* __restrict__ gamma,
                          const float* __restrict__ beta, int applyBN,
                          float* __restrict__ aggr, long total4){
  for(long i = (long)blockIdx.x*blockDim.x + threadIdx.x; i < total4; i += (long)gridDim.x*blockDim.x){
    int c0 = ((int)(i & 63)) << 2;
    float4 v = ((const float4*)h)[i];
    float o[4] = {v.x, v.y, v.z, v.w};
#pragma unroll
    for(int c=0;c<4;c++){
      float x = o[c];
      if(applyBN){
        x = gamma[c0+c]*(x - musig[c0+c])*musig[256+c0+c] + beta[c0+c];
        x = x > 0.f ? x : 0.f;
      }
      o[c] = x + sl[c0+c];
    }
    float4 ov = {o[0], o[1], o[2], o[3]};
    ((float4*)aggr)[i] = ov;
  }
}

// ---------------- edge MLP + gather + atomic scatter ----------------

__global__ __launch_bounds__(256,2) void edge_mlp_scatter(
    const unsigned short* __restrict__ eb,
    const unsigned short* __restrict__ w1T, const float* __restrict__ b1,
    const unsigned short* __restrict__ w2T, const float* __restrict__ b2,
    const int* __restrict__ b2a, const int* __restrict__ to,
    const float* __restrict__ hraw,
    const float* __restrict__ musig, const float* __restrict__ gamma,
    const float* __restrict__ beta, int applyBN,
    float* __restrict__ aggr, int E)
{
  __shared__ alignas(16) unsigned short sEB[64*32];
  __shared__ alignas(16) unsigned short sH[64*256];
  __shared__ int sB2A[64], sTO[64];
  const int t  = threadIdx.x;
  const int e0 = blockIdx.x*64;
  {
    int row = t >> 2;
    int kc  = (t & 3) << 3;            // 0,8,16,24
    uint4 val = make_uint4(0,0,0,0);
    int e = e0 + row;
    if(kc < 16 && e < E) val = *(const uint4*)(eb + (size_t)e*16 + kc);
    *(uint4*)((char*)sEB + swzb(row, kc*2, 64)) = val;
  }
  if(t < 64){
    int e = e0 + t;
    sB2A[t] = (e < E) ? b2a[e] : 0;
    sTO[t]  = (e < E) ? to[e]  : 0;
  }
  __syncthreads();

  const int w = t>>6, l = t&63, lg = l>>4, lc = l&15;
  const f32x4 z4 = {0.f,0.f,0.f,0.f};

  { // stage 1: hid1 = relu(eb @ w1 + b1) -> sH (bf16)
    bf16x8 a[4], b[4];
#pragma unroll
    for(int fi=0;fi<4;fi++)
      a[fi] = *(const bf16x8*)((const char*)sEB + swzb(fi*16+lc, lg*16, 64));
#pragma unroll
    for(int fj=0;fj<4;fj++){
      int col = w*64 + fj*16 + lc;
      b[fj] = *(const bf16x8*)(w1T + (size_t)col*KB_PAD + lg*8);
    }
    f32x4 s1[4][4];
#pragma unroll
    for(int fi=0;fi<4;fi++)
#pragma unroll
      for(int fj=0;fj<4;fj++)
        s1[fi][fj] = mfma16(a[fi], b[fj], z4);
#pragma unroll
    for(int fj=0;fj<4;fj++){
      int col = w*64 + fj*16 + lc;
      float bias = b1[col];
#pragma unroll
      for(int fi=0;fi<4;fi++)
#pragma unroll
        for(int r=0;r<4;r++){
          int row = fi*16 + lg*4 + r;
          float v = s1[fi][fj][r] + bias;
          v = v > 0.f ? v : 0.f;
          *(unsigned short*)((char*)sH + swzb(row, col*2, 512)) = f2bf(v);
        }
    }
  }
  __syncthreads();

  // stage 2: e_emb = hid1 @ w2
  f32x4 acc[4][4];
#pragma unroll
  for(int fi=0;fi<4;fi++)
#pragma unroll
    for(int fj=0;fj<4;fj++) acc[fi][fj] = z4;
  for(int k0=0;k0<256;k0+=32){
    bf16x8 a[4], b[4];
#pragma unroll
    for(int fi=0;fi<4;fi++)
      a[fi] = *(const bf16x8*)((const char*)sH + swzb(fi*16+lc, (k0+lg*8)*2, 512));
#pragma unroll
    for(int fj=0;fj<4;fj++){
      int col = w*64 + fj*16 + lc;
      b[fj] = *(const bf16x8*)(w2T + (size_t)col*256 + k0 + lg*8);
    }
#pragma unroll
    for(int fi=0;fi<4;fi++)
#pragma unroll
      for(int fj=0;fj<4;fj++)
        acc[fi][fj] = mfma16(a[fi], b[fj], acc[fi][fj]);
  }

  // epilogue: msg = e_emb + b2 + BNprev(h[b2a]); atomicAdd into aggr[to]
  float bb[4], g4[4], mu4[4], rs4[4], be4[4];
#pragma unroll
  for(int fj=0;fj<4;fj++){
    int col = w*64 + fj*16 + lc;
    bb[fj] = b2[col];
    if(applyBN){
      g4[fj] = gamma[col]; mu4[fj] = musig[col];
      rs4[fj] = musig[256+col]; be4[fj] = beta[col];
    }
  }
#pragma unroll
  for(int fi=0;fi<4;fi++){
#pragma unroll
    for(int r=0;r<4;r++){
      int row = fi*16 + lg*4 + r;
      int e = e0 + row;
      if(e < E){
        const float* hp = hraw + (size_t)sB2A[row]*HID;
        float*       ap = aggr + (size_t)sTO[row]*HID;
#pragma unroll
        for(int fj=0;fj<4;fj++){
          int col = w*64 + fj*16 + lc;
          float hv = hp[col];
          if(applyBN){
            hv = g4[fj]*(hv - mu4[fj])*rs4[fj] + be4[fj];
            hv = hv > 0.f ? hv : 0.f;
          }
          atomicAdd(ap + col, acc[fi][fj][r] + bb[fj] + hv);
        }
      }
    }
  }
}

// ---------------- node MLP + BN stats ----------------

__global__ __launch_bounds__(256,2) void node_mlp(
    const float* __restrict__ aggr,
    const unsigned short* __restrict__ m1T, const float* __restrict__ b1,
    const unsigned short* __restrict__ m2T, const float* __restrict__ b2,
    float* __restrict__ z, float* __restrict__ stats, int N)
{
  __shared__ alignas(16) unsigned short sA [64*256];
  __shared__ alignas(16) unsigned short sHD[64*128];
  const int t  = threadIdx.x;
  const int m0 = blockIdx.x*64;
  {
    int row = t >> 2;
    int kb  = (t & 3) << 6;
    int gr  = m0 + row;
    bool ok = gr < N;
    const float* ap = aggr + (size_t)gr*HID;
#pragma unroll
    for(int j=0;j<8;j++){
      int k = kb + j*8;
      union { unsigned short us[8]; uint4 v; } pk;
      if(ok){
        float4 v0 = *(const float4*)(ap + k);
        float4 v1 = *(const float4*)(ap + k + 4);
        pk.us[0]=f2bf(v0.x); pk.us[1]=f2bf(v0.y); pk.us[2]=f2bf(v0.z); pk.us[3]=f2bf(v0.w);
        pk.us[4]=f2bf(v1.x); pk.us[5]=f2bf(v1.y); pk.us[6]=f2bf(v1.z); pk.us[7]=f2bf(v1.w);
      } else {
        pk.v = make_uint4(0,0,0,0);
      }
      *(uint4*)((char*)sA + swzb(row, k*2, 512)) = pk.v;
    }
  }
  __syncthreads();
  const int w = t>>6, l = t&63, lg = l>>4, lc = l&15;
  const f32x4 z4 = {0.f,0.f,0.f,0.f};
  f32x4 zacc[4][4];
#pragma unroll
  for(int fi=0;fi<4;fi++)
#pragma unroll
    for(int fj=0;fj<4;fj++) zacc[fi][fj] = z4;

  for(int c=0;c<4;c++){
    // stage 1 chunk: hid[:, c*128 .. c*128+128)
    f32x4 h1[4][2];
#pragma unroll
    for(int fi=0;fi<4;fi++){ h1[fi][0] = z4; h1[fi][1] = z4; }
    for(int k0=0;k0<256;k0+=32){
      bf16x8 a[4];
#pragma unroll
      for(int fi=0;fi<4;fi++)
        a[fi] = *(const bf16x8*)((const char*)sA + swzb(fi*16+lc, (k0+lg*8)*2, 512));
#pragma unroll
      for(int fj=0;fj<2;fj++){
        int col = c*128 + w*32 + fj*16 + lc;
        bf16x8 b = *(const bf16x8*)(m1T + (size_t)col*256 + k0 + lg*8);
#pragma unroll
        for(int fi=0;fi<4;fi++)
          h1[fi][fj] = mfma16(a[fi], b, h1[fi][fj]);
      }
    }
    __syncthreads();   // previous chunk's sHD fully consumed
#pragma unroll
    for(int fj=0;fj<2;fj++){
      int col  = c*128 + w*32 + fj*16 + lc;
      int lcol = w*32 + fj*16 + lc;
      float bias = b1[col];
#pragma unroll
      for(int fi=0;fi<4;fi++)
#pragma unroll
        for(int r=0;r<4;r++){
          int row = fi*16 + lg*4 + r;
          float v = h1[fi][fj][r] + bias;
          v = v > 0.f ? v : 0.f;
          *(unsigned short*)((char*)sHD + swzb(row, lcol*2, 256)) = f2bf(v);
        }
    }
    __syncthreads();
    // stage 2: z += hid_chunk @ w2[chunk]
    for(int k0=0;k0<128;k0+=32){
      bf16x8 a[4], b[4];
#pragma unroll
      for(int fi=0;fi<4;fi++)
        a[fi] = *(const bf16x8*)((const char*)sHD + swzb(fi*16+lc, (k0+lg*8)*2, 256));
#pragma unroll
      for(int fj=0;fj<4;fj++){
        int col = w*64 + fj*16 + lc;
        b[fj] = *(const bf16x8*)(m2T + (size_t)col*512 + c*128 + k0 + lg*8);
      }
#pragma unroll
      for(int fi=0;fi<4;fi++)
#pragma unroll
        for(int fj=0;fj<4;fj++)
          zacc[fi][fj] = mfma16(a[fi], b[fj], zacc[fi][fj]);
    }
  }

  // epilogue: z store + column stats (sum, sumsq)
#pragma unroll
  for(int fj=0;fj<4;fj++){
    int col = w*64 + fj*16 + lc;
    float bias = b2[col];
    float s1 = 0.f, s2 = 0.f;
#pragma unroll
    for(int fi=0;fi<4;fi++)
#pragma unroll
      for(int r=0;r<4;r++){
        int gr = m0 + fi*16 + lg*4 + r;
        float v = zacc[fi][fj][r] + bias;
        if(gr < N){
          z[(size_t)gr*HID + col] = v;
          s1 += v; s2 += v*v;
        }
      }
    s1 += __shfl_xor(s1, 16, 64); s1 += __shfl_xor(s1, 32, 64);
    s2 += __shfl_xor(s2, 16, 64); s2 += __shfl_xor(s2, 32, 64);
    if(lg == 0){
      atomicAdd(&stats[col],       s1);
      atomicAdd(&stats[HID + col], s2);
    }
  }
}

__global__ void stats_fin(const float* __restrict__ stats, float* __restrict__ musig, float invN){
  int c = threadIdx.x;
  float mu  = stats[c] * invN;
  float var = stats[HID + c] * invN - mu*mu;
  musig[c]       = mu;
  musig[HID + c] = rsqrtf(var + BN_EPS);
}

__global__ void final_bn(float* __restrict__ out, const float* __restrict__ musig,
                         const float* __restrict__ gamma, const float* __restrict__ beta,
                         long total4){
  for(long i = (long)blockIdx.x*blockDim.x + threadIdx.x; i < total4; i += (long)gridDim.x*blockDim.x){
    int c0 = ((int)(i & 63)) << 2;
    float4 v = ((const float4*)out)[i];
    float o[4] = {v.x, v.y, v.z, v.w};
#pragma unroll
    for(int c=0;c<4;c++)
      o[c] = gamma[c0+c]*(o[c] - musig[c0+c])*musig[256+c0+c] + beta[c0+c];
    float4 ov = {o[0], o[1], o[2], o[3]};
    ((float4*)out)[i] = ov;
  }
}

// ---------------- host ----------------

extern "C" void kernel_launch(void* const* d_in, const int* in_sizes, int n_in,
                              void* d_out, int out_size, void* d_ws, size_t ws_size,
                              hipStream_t stream)
{
  const float* f_atoms = (const float*)d_in[0];
  const float* f_bonds = (const float*)d_in[1];
  const int*   a2b     = (const int*)d_in[2];
  const int*   b2a     = (const int*)d_in[3];
  const float* w_atom  = (const float*)d_in[6];
  const float* wb_w1   = (const float*)d_in[7];
  const float* wb_b1   = (const float*)d_in[8];
  const float* wb_w2   = (const float*)d_in[9];
  const float* wb_b2   = (const float*)d_in[10];
  const float* mlp_w1  = (const float*)d_in[11];
  const float* mlp_b1  = (const float*)d_in[12];
  const float* mlp_w2  = (const float*)d_in[13];
  const float* mlp_b2  = (const float*)d_in[14];
  const float* bn_g    = (const float*)d_in[15];
  const float* bn_b    = (const float*)d_in[16];
  const int N = in_sizes[0] / AFD;
  const int E = in_sizes[3];
  float* out = (float*)d_out;
  (void)n_in; (void)out_size; (void)ws_size;

  char* ws = (char*)d_ws;
  size_t off = 0;
  auto alloc = [&](size_t bytes)->char* {
    char* p = ws + off; off += (bytes + 255) & ~(size_t)255; return p;
  };
  float* hbuf          = (float*)alloc((size_t)N*HID*4);
  float* aggr          = (float*)alloc((size_t)N*HID*4);
  unsigned short* eb   = (unsigned short*)alloc((size_t)E*16*2);
  int* to              = (int*)alloc((size_t)E*4);
  unsigned short* wAT  = (unsigned short*)alloc((size_t)HID*KA_PAD*2);
  unsigned short* w1T  = (unsigned short*)alloc((size_t)3*HID*KB_PAD*2);
  unsigned short* w2T  = (unsigned short*)alloc((size_t)3*HID*HID*2);
  unsigned short* m1T  = (unsigned short*)alloc((size_t)3*512*HID*2);
  unsigned short* m2T  = (unsigned short*)alloc((size_t)3*HID*512*2);
  float* sl            = (float*)alloc((size_t)3*HID*4);
  float* stats         = (float*)alloc((size_t)3*512*4);
  float* musig         = (float*)alloc((size_t)3*512*4);

  hipMemsetAsync(stats, 0, (size_t)3*512*4, stream);
  hipMemsetAsync(to, 0, (size_t)E*4, stream);

  auto cdiv = [](long a, long b){ return (int)((a + b - 1)/b); };

  pack_wT<<<cdiv((long)HID*KA_PAD,256),256,0,stream>>>(w_atom, wAT, AFD, HID, KA_PAD);
  for(int l=0;l<3;l++){
    pack_wT<<<cdiv((long)HID*KB_PAD,256),256,0,stream>>>(wb_w1 + (size_t)l*16*HID,  w1T + (size_t)l*HID*KB_PAD, 16,  HID, KB_PAD);
    pack_wT<<<cdiv((long)HID*HID,256),256,0,stream>>>(wb_w2 + (size_t)l*HID*HID,  w2T + (size_t)l*HID*HID,  HID, HID, HID);
    pack_wT<<<cdiv((long)512*HID,256),256,0,stream>>>(mlp_w1 + (size_t)l*HID*512, m1T + (size_t)l*512*HID,  HID, 512, HID);
    pack_wT<<<cdiv((long)HID*512,256),256,0,stream>>>(mlp_w2 + (size_t)l*512*HID, m2T + (size_t)l*HID*512,  512, HID, 512);
  }
  pack_eb<<<2048,256,0,stream>>>(f_bonds, eb, E);
  build_to<<<2048,256,0,stream>>>(a2b, to, N);
  sl_emb_kernel<<<3,256,0,stream>>>(wb_w1, wb_b1, wb_w2, wb_b2, sl);

  atom_embed<<<cdiv(N,64),256,0,stream>>>(f_atoms, wAT, hbuf, N);

  float* hraw = hbuf;
  float* zdst = out;
  for(int l=0;l<3;l++){
    int applyBN = (l > 0);
    const float* ms = applyBN ? (musig + (size_t)(l-1)*512) : musig;
    const float* gp = applyBN ? (bn_g + (size_t)(l-1)*HID)  : bn_g;
    const float* bp = applyBN ? (bn_b + (size_t)(l-1)*HID)  : bn_b;
    aggr_init<<<2048,256,0,stream>>>(hraw, sl + (size_t)l*HID, ms, gp, bp, applyBN, aggr, (long)N*64);
    edge_mlp_scatter<<<cdiv(E,64),256,0,stream>>>(eb,
        w1T + (size_t)l*HID*KB_PAD, wb_b1 + (size_t)l*HID,
        w2T + (size_t)l*HID*HID,    wb_b2 + (size_t)l*HID,
        b2a, to, hraw, ms, gp, bp, applyBN, aggr, E);
    node_mlp<<<cdiv(N,64),256,0,stream>>>(aggr,
        m1T + (size_t)l*512*HID, mlp_b1 + (size_t)l*512,
        m2T + (size_t)l*HID*512, mlp_b2 + (size_t)l*HID,
        zdst, stats + (size_t)l*512, N);
    stats_fin<<<1,256,0,stream>>>(stats + (size_t)l*512, musig + (size_t)l*512, 1.0f/(float)N);
    float* tmp = hraw; hraw = zdst; zdst = tmp;
  }
  final_bn<<<2048,256,0,stream>>>(out, musig + 2*512, bn_g + 2*HID, bn_b + 2*HID, (long)N*64);
}